// Round 4
// baseline (423.545 us; speedup 1.0000x reference)
//
#include <hip/hip_runtime.h>

#define NN 50000
#define NE 320000
#define FF 256
#define SCAN_B 196   // ceil(NN/256)

typedef short short8 __attribute__((ext_vector_type(8)));
typedef float f32x4 __attribute__((ext_vector_type(4)));
typedef unsigned short us4 __attribute__((ext_vector_type(4)));

static __device__ __forceinline__ unsigned short f2bf(float f) {
    union { float f; unsigned u; } v; v.f = f;
    unsigned r = v.u + 0x7FFFu + ((v.u >> 16) & 1u);   // RNE
    return (unsigned short)(r >> 16);
}

// ---------------- degree (int histogram over dst) ----------------
__global__ void k_deg(const int* __restrict__ ei, int* __restrict__ deg) {
    int e = blockIdx.x * blockDim.x + threadIdx.x;
    if (e < NE) atomicAdd(&deg[ei[NE + e]], 1);
}

// ---------------- hierarchical scan: block sums -> scan sums -> local scan ----------------
__global__ void k_scan1(const int* __restrict__ deg, int* __restrict__ bsum) {
    __shared__ int s[256];
    int i = blockIdx.x * 256 + threadIdx.x;
    s[threadIdx.x] = (i < NN) ? deg[i] : 0;
    __syncthreads();
    for (int d = 128; d > 0; d >>= 1) {
        if (threadIdx.x < d) s[threadIdx.x] += s[threadIdx.x + d];
        __syncthreads();
    }
    if (threadIdx.x == 0) bsum[blockIdx.x] = s[0];
}

__global__ void k_scan2(const int* __restrict__ bsum, int* __restrict__ boff) {
    __shared__ int s[256];
    int t = threadIdx.x;
    int v = (t < SCAN_B) ? bsum[t] : 0;
    s[t] = v;
    __syncthreads();
    for (int d = 1; d < 256; d <<= 1) {
        int u = (t >= d) ? s[t - d] : 0;
        __syncthreads();
        s[t] += u;
        __syncthreads();
    }
    if (t < SCAN_B) boff[t] = s[t] - v;
}

__global__ void k_scan3(const int* __restrict__ deg, const int* __restrict__ boff,
                        int* __restrict__ off, int* __restrict__ cur,
                        float* __restrict__ dinv) {
    __shared__ int s[256];
    int t = threadIdx.x;
    int i = blockIdx.x * 256 + t;
    int v = (i < NN) ? deg[i] : 0;
    s[t] = v;
    __syncthreads();
    for (int d = 1; d < 256; d <<= 1) {
        int u = (t >= d) ? s[t - d] : 0;
        __syncthreads();
        s[t] += u;
        __syncthreads();
    }
    if (i < NN) {
        int excl = boff[blockIdx.x] + s[t] - v;
        off[i] = excl;
        cur[i] = excl;
        dinv[i] = v > 0 ? rsqrtf((float)v) : 0.f;
    }
}

// ---------------- CSR fill ----------------
__global__ void k_fill(const int* __restrict__ ei, int* __restrict__ cur,
                       int* __restrict__ csr_src) {
    int e = blockIdx.x * blockDim.x + threadIdx.x;
    if (e < NE) {
        int dst = ei[NE + e];
        int pos = atomicAdd(&cur[dst], 1);
        csr_src[pos] = ei[e];
    }
}

// ---------------- aggregation (one wave/node) + fused x->bf16 conversion ----------------
__global__ __launch_bounds__(256)
void k_agg(const int* __restrict__ off, const int* __restrict__ deg,
           const int* __restrict__ csr_src, const float* __restrict__ dinv,
           const float* __restrict__ x, unsigned short* __restrict__ Ab) {
    int wid = (blockIdx.x * blockDim.x + threadIdx.x) >> 6;
    if (wid >= NN) return;
    int lane = threadIdx.x & 63;
    int start = off[wid];
    int d = deg[wid];
    float di = dinv[wid];
    float4 acc = make_float4(0.f, 0.f, 0.f, 0.f);
    int e = 0;
    for (; e + 2 <= d; e += 2) {
        int s0 = csr_src[start + e];
        int s1 = csr_src[start + e + 1];
        float w0 = di * dinv[s0];
        float w1 = di * dinv[s1];
        float4 v0 = *reinterpret_cast<const float4*>(&x[(size_t)s0 * FF + lane * 4]);
        float4 v1 = *reinterpret_cast<const float4*>(&x[(size_t)s1 * FF + lane * 4]);
        acc.x = fmaf(w0, v0.x, fmaf(w1, v1.x, acc.x));
        acc.y = fmaf(w0, v0.y, fmaf(w1, v1.y, acc.y));
        acc.z = fmaf(w0, v0.z, fmaf(w1, v1.z, acc.z));
        acc.w = fmaf(w0, v0.w, fmaf(w1, v1.w, acc.w));
    }
    if (e < d) {
        int s0 = csr_src[start + e];
        float w0 = di * dinv[s0];
        float4 v0 = *reinterpret_cast<const float4*>(&x[(size_t)s0 * FF + lane * 4]);
        acc.x = fmaf(w0, v0.x, acc.x);
        acc.y = fmaf(w0, v0.y, acc.y);
        acc.z = fmaf(w0, v0.z, acc.z);
        acc.w = fmaf(w0, v0.w, acc.w);
    }
    us4 o = {f2bf(acc.x), f2bf(acc.y), f2bf(acc.z), f2bf(acc.w)};
    *reinterpret_cast<us4*>(Ab + (size_t)wid * 512 + lane * 4) = o;
    // fused k_xcvt: x-half (cols 256..511)
    float4 xv = *reinterpret_cast<const float4*>(&x[(size_t)wid * FF + lane * 4]);
    us4 ox = {f2bf(xv.x), f2bf(xv.y), f2bf(xv.z), f2bf(xv.w)};
    *reinterpret_cast<us4*>(Ab + (size_t)wid * 512 + 256 + lane * 4) = ox;
}

// ---------------- B prep: fragment-linear bf16 Bp [fb = kc*32+cf][lane][8] ----------------
__global__ void k_bprep(const float* __restrict__ wi, const float* __restrict__ wr,
                        unsigned short* __restrict__ Bp) {
    int t = blockIdx.x * blockDim.x + threadIdx.x;   // 0..32767
    int l = t & 63;
    int fb = t >> 6;          // 0..511
    int kc = fb >> 5;
    int cf = fb & 31;
    int col = cf * 16 + (l & 15);
    int kpart = col >> 8;
    int g = col & 255;
    int K0 = kc * 32 + (l >> 4) * 8;
    unsigned short* dst = Bp + (size_t)fb * 512 + (size_t)l * 8;
    #pragma unroll
    for (int e = 0; e < 8; ++e) {
        int K = K0 + e;
        const float* srcp = (K < 256) ? wi : wr;
        float v = srcp[(size_t)kpart * 65536 + (size_t)(K & 255) * 256 + g];
        dst[e] = f2bf(v);
    }
}

// ---------------- MFMA GEMM + epilogue, register double-buffered ----------------
struct Frags { short8 a[4]; short8 b[8]; };

__device__ __forceinline__ void load_frags(Frags& F, const unsigned short* const ap[4],
                                           const unsigned short* bp, int w, int kc) {
    #pragma unroll
    for (int rf = 0; rf < 4; ++rf)
        F.a[rf] = *reinterpret_cast<const short8*>(ap[rf] + kc * 32);
    #pragma unroll
    for (int c = 0; c < 8; ++c) {
        int cf = (c < 4) ? (w * 4 + c) : (12 + w * 4 + c);   // c>=4 -> 16 + w*4 + (c-4)
        F.b[c] = *reinterpret_cast<const short8*>(bp + (size_t)(kc * 32 + cf) * 512);
    }
}

__device__ __forceinline__ void do_mfma(f32x4 acc[4][8], const Frags& F) {
    #pragma unroll
    for (int rf = 0; rf < 4; ++rf)
        #pragma unroll
        for (int c = 0; c < 8; ++c)
            acc[rf][c] = __builtin_amdgcn_mfma_f32_16x16x32_bf16(F.a[rf], F.b[c], acc[rf][c], 0, 0, 0);
}

__global__ __launch_bounds__(256, 3)
void k_mm(const unsigned short* __restrict__ Ab, const unsigned short* __restrict__ Bp,
          const float* __restrict__ x, const float* __restrict__ bias,
          float* __restrict__ out) {
    const int l = threadIdx.x & 63;
    const int w = threadIdx.x >> 6;
    const int row0 = blockIdx.x * 64;
    const int rA = l & 15;
    const int kA = (l >> 4) * 8;

    f32x4 acc[4][8];
    #pragma unroll
    for (int i = 0; i < 4; ++i)
        #pragma unroll
        for (int j = 0; j < 8; ++j) acc[i][j] = (f32x4){0.f, 0.f, 0.f, 0.f};

    const unsigned short* ap[4];
    #pragma unroll
    for (int rf = 0; rf < 4; ++rf) {
        int r = row0 + rf * 16 + rA;
        if (r >= NN) r = NN - 1;                  // clamp tail rows (stores masked below)
        ap[rf] = Ab + (size_t)r * 512 + kA;
    }
    const unsigned short* bp = Bp + (size_t)l * 8;

    Frags f0, f1;
    load_frags(f0, ap, bp, w, 0);
    #pragma unroll 1
    for (int kc = 0; kc < 16; kc += 2) {
        load_frags(f1, ap, bp, w, kc + 1);
        do_mfma(acc, f0);
        if (kc + 2 < 16) load_frags(f0, ap, bp, w, kc + 2);
        do_mfma(acc, f1);
    }

    __syncthreads();   // Ab aliases out: all waves' A reads must finish before stores

    #pragma unroll
    for (int rf = 0; rf < 4; ++rf) {
        const int rb = row0 + rf * 16 + (l >> 4) * 4;
        #pragma unroll
        for (int c = 0; c < 4; ++c) {
            const int gg = w * 64 + c * 16 + (l & 15);
            const float b0 = bias[gg], b1 = bias[256 + gg];
            #pragma unroll
            for (int j = 0; j < 4; ++j) {
                int r = rb + j;
                if (r < NN) {
                    float c0 = acc[rf][c][j] + b0;
                    float c1 = acc[rf][c + 4][j] + b1;
                    float arma = 0.5f * (fmaxf(c0, 0.f) + fmaxf(c1, 0.f));
                    out[(size_t)r * FF + gg] = x[(size_t)r * FF + gg] + fmaxf(arma, 0.f);
                }
            }
        }
    }
}

extern "C" void kernel_launch(void* const* d_in, const int* in_sizes, int n_in,
                              void* d_out, int out_size, void* d_ws, size_t ws_size,
                              hipStream_t stream) {
    const float* x    = (const float*)d_in[0];
    const int*   ei   = (const int*)d_in[1];
    const float* wi   = (const float*)d_in[2];
    const float* wr   = (const float*)d_in[3];
    const float* bias = (const float*)d_in[4];
    float* out = (float*)d_out;

    // workspace (~2.6 MB)
    int*   deg     = (int*)d_ws;              // NN
    int*   off     = deg + NN;                // NN
    int*   cur     = off + NN;                // NN
    int*   csr_src = cur + NN;                // NE
    float* dinv    = (float*)(csr_src + NE);  // NN
    int*   bsum    = (int*)(dinv + NN);       // SCAN_B
    int*   boff    = bsum + SCAN_B;           // SCAN_B
    unsigned short* Bp = (unsigned short*)(boff + SCAN_B);   // 512*512 bf16 = 512 KB
    unsigned short* Ab = (unsigned short*)d_out;             // 50000 x 512 bf16 == d_out bytes

    hipMemsetAsync(deg, 0, NN * sizeof(int), stream);

    k_deg  <<<(NE + 255) / 256, 256, 0, stream>>>(ei, deg);
    k_scan1<<<SCAN_B, 256, 0, stream>>>(deg, bsum);
    k_scan2<<<1, 256, 0, stream>>>(bsum, boff);
    k_scan3<<<SCAN_B, 256, 0, stream>>>(deg, boff, off, cur, dinv);
    k_fill <<<(NE + 255) / 256, 256, 0, stream>>>(ei, cur, csr_src);
    k_bprep<<<128, 256, 0, stream>>>(wi, wr, Bp);
    k_agg  <<<(NN * 64 + 255) / 256, 256, 0, stream>>>(off, deg, csr_src, dinv, x, Ab);
    k_mm   <<<(NN + 63) / 64, 256, 0, stream>>>(Ab, Bp, x, bias, out);
}

// Round 5
// 192.197 us; speedup vs baseline: 2.2037x; 2.2037x over previous
//
#include <hip/hip_runtime.h>

#define NN 50000
#define NE 320000
#define FF 256
#define SCAN_B 196   // ceil(NN/256)

typedef short short8 __attribute__((ext_vector_type(8)));
typedef float f32x4 __attribute__((ext_vector_type(4)));
typedef unsigned short us4 __attribute__((ext_vector_type(4)));

static __device__ __forceinline__ unsigned short f2bf(float f) {
    union { float f; unsigned u; } v; v.f = f;
    unsigned r = v.u + 0x7FFFu + ((v.u >> 16) & 1u);   // RNE
    return (unsigned short)(r >> 16);
}

// ---------------- degree (int histogram over dst) ----------------
__global__ void k_deg(const int* __restrict__ ei, int* __restrict__ deg) {
    int e = blockIdx.x * blockDim.x + threadIdx.x;
    if (e < NE) atomicAdd(&deg[ei[NE + e]], 1);
}

// ---------------- hierarchical scan: block sums -> scan sums -> local scan ----------------
__global__ void k_scan1(const int* __restrict__ deg, int* __restrict__ bsum) {
    __shared__ int s[256];
    int i = blockIdx.x * 256 + threadIdx.x;
    s[threadIdx.x] = (i < NN) ? deg[i] : 0;
    __syncthreads();
    for (int d = 128; d > 0; d >>= 1) {
        if (threadIdx.x < d) s[threadIdx.x] += s[threadIdx.x + d];
        __syncthreads();
    }
    if (threadIdx.x == 0) bsum[blockIdx.x] = s[0];
}

__global__ void k_scan2(const int* __restrict__ bsum, int* __restrict__ boff) {
    __shared__ int s[256];
    int t = threadIdx.x;
    int v = (t < SCAN_B) ? bsum[t] : 0;
    s[t] = v;
    __syncthreads();
    for (int d = 1; d < 256; d <<= 1) {
        int u = (t >= d) ? s[t - d] : 0;
        __syncthreads();
        s[t] += u;
        __syncthreads();
    }
    if (t < SCAN_B) boff[t] = s[t] - v;
}

__global__ void k_scan3(const int* __restrict__ deg, const int* __restrict__ boff,
                        int* __restrict__ off, int* __restrict__ cur,
                        float* __restrict__ dinv) {
    __shared__ int s[256];
    int t = threadIdx.x;
    int i = blockIdx.x * 256 + t;
    int v = (i < NN) ? deg[i] : 0;
    s[t] = v;
    __syncthreads();
    for (int d = 1; d < 256; d <<= 1) {
        int u = (t >= d) ? s[t - d] : 0;
        __syncthreads();
        s[t] += u;
        __syncthreads();
    }
    if (i < NN) {
        int excl = boff[blockIdx.x] + s[t] - v;
        off[i] = excl;
        cur[i] = excl;
        dinv[i] = v > 0 ? rsqrtf((float)v) : 0.f;
    }
}

// ---------------- CSR fill ----------------
__global__ void k_fill(const int* __restrict__ ei, int* __restrict__ cur,
                       int* __restrict__ csr_src) {
    int e = blockIdx.x * blockDim.x + threadIdx.x;
    if (e < NE) {
        int dst = ei[NE + e];
        int pos = atomicAdd(&cur[dst], 1);
        csr_src[pos] = ei[e];
    }
}

// ---------------- aggregation (one wave/node) + fused x->bf16 conversion ----------------
__global__ __launch_bounds__(256)
void k_agg(const int* __restrict__ off, const int* __restrict__ deg,
           const int* __restrict__ csr_src, const float* __restrict__ dinv,
           const float* __restrict__ x, unsigned short* __restrict__ Ab) {
    int wid = (blockIdx.x * blockDim.x + threadIdx.x) >> 6;
    if (wid >= NN) return;
    int lane = threadIdx.x & 63;
    int start = off[wid];
    int d = deg[wid];
    float di = dinv[wid];
    float4 acc = make_float4(0.f, 0.f, 0.f, 0.f);
    int e = 0;
    for (; e + 2 <= d; e += 2) {
        int s0 = csr_src[start + e];
        int s1 = csr_src[start + e + 1];
        float w0 = di * dinv[s0];
        float w1 = di * dinv[s1];
        float4 v0 = *reinterpret_cast<const float4*>(&x[(size_t)s0 * FF + lane * 4]);
        float4 v1 = *reinterpret_cast<const float4*>(&x[(size_t)s1 * FF + lane * 4]);
        acc.x = fmaf(w0, v0.x, fmaf(w1, v1.x, acc.x));
        acc.y = fmaf(w0, v0.y, fmaf(w1, v1.y, acc.y));
        acc.z = fmaf(w0, v0.z, fmaf(w1, v1.z, acc.z));
        acc.w = fmaf(w0, v0.w, fmaf(w1, v1.w, acc.w));
    }
    if (e < d) {
        int s0 = csr_src[start + e];
        float w0 = di * dinv[s0];
        float4 v0 = *reinterpret_cast<const float4*>(&x[(size_t)s0 * FF + lane * 4]);
        acc.x = fmaf(w0, v0.x, acc.x);
        acc.y = fmaf(w0, v0.y, acc.y);
        acc.z = fmaf(w0, v0.z, acc.z);
        acc.w = fmaf(w0, v0.w, acc.w);
    }
    us4 o = {f2bf(acc.x), f2bf(acc.y), f2bf(acc.z), f2bf(acc.w)};
    *reinterpret_cast<us4*>(Ab + (size_t)wid * 512 + lane * 4) = o;
    // fused x->bf16: x-half (cols 256..511)
    float4 xv = *reinterpret_cast<const float4*>(&x[(size_t)wid * FF + lane * 4]);
    us4 ox = {f2bf(xv.x), f2bf(xv.y), f2bf(xv.z), f2bf(xv.w)};
    *reinterpret_cast<us4*>(Ab + (size_t)wid * 512 + 256 + lane * 4) = ox;
}

// ---------------- B prep: fragment-linear bf16 Bp [fb = kc*32+cf][lane][8] ----------------
__global__ void k_bprep(const float* __restrict__ wi, const float* __restrict__ wr,
                        unsigned short* __restrict__ Bp) {
    int t = blockIdx.x * blockDim.x + threadIdx.x;   // 0..32767
    int l = t & 63;
    int fb = t >> 6;          // 0..511
    int kc = fb >> 5;
    int cf = fb & 31;
    int col = cf * 16 + (l & 15);
    int kpart = col >> 8;
    int g = col & 255;
    int K0 = kc * 32 + (l >> 4) * 8;
    unsigned short* dst = Bp + (size_t)fb * 512 + (size_t)l * 8;
    #pragma unroll
    for (int e = 0; e < 8; ++e) {
        int K = K0 + e;
        const float* srcp = (K < 256) ? wi : wr;
        float v = srcp[(size_t)kpart * 65536 + (size_t)(K & 255) * 256 + g];
        dst[e] = f2bf(v);
    }
}

// ---------------- MFMA GEMM + epilogue, explicit ping-pong pipeline ----------------
// Block: 64 rows, 4 waves; wave w covers cols [w*64, w*64+64) for k=0 and k=1.
#define LOADA(dst, kc_)                                                          \
    {                                                                            \
        _Pragma("unroll")                                                        \
        for (int rf = 0; rf < 4; ++rf)                                           \
            dst[rf] = *reinterpret_cast<const short8*>(ap[rf] + (kc_) * 32);     \
    }
#define LOADB(dst, kc_)                                                          \
    {                                                                            \
        _Pragma("unroll")                                                        \
        for (int c = 0; c < 8; ++c) {                                            \
            int cf = (c < 4) ? (w * 4 + c) : (12 + w * 4 + c);                   \
            dst[c] = *reinterpret_cast<const short8*>(bp + (size_t)((kc_) * 32 + cf) * 512); \
        }                                                                        \
    }
#define MFMA_HALF(aset, bset, rf0, rf1)                                          \
    {                                                                            \
        _Pragma("unroll")                                                        \
        for (int c = 0; c < 8; ++c)                                              \
            acc[rf0][c] = __builtin_amdgcn_mfma_f32_16x16x32_bf16(aset[rf0], bset[c], acc[rf0][c], 0, 0, 0); \
        _Pragma("unroll")                                                        \
        for (int c = 0; c < 8; ++c)                                              \
            acc[rf1][c] = __builtin_amdgcn_mfma_f32_16x16x32_bf16(aset[rf1], bset[c], acc[rf1][c], 0, 0, 0); \
    }

__global__ __launch_bounds__(256, 2)
void k_mm(const unsigned short* __restrict__ Ab, const unsigned short* __restrict__ Bp,
          const float* __restrict__ x, const float* __restrict__ bias,
          float* __restrict__ out) {
    const int l = threadIdx.x & 63;
    const int w = threadIdx.x >> 6;
    const int row0 = blockIdx.x * 64;
    const int rA = l & 15;
    const int kA = (l >> 4) * 8;

    f32x4 acc[4][8];
    #pragma unroll
    for (int i = 0; i < 4; ++i)
        #pragma unroll
        for (int j = 0; j < 8; ++j) acc[i][j] = (f32x4){0.f, 0.f, 0.f, 0.f};

    const unsigned short* ap[4];
    #pragma unroll
    for (int rf = 0; rf < 4; ++rf) {
        int r = row0 + rf * 16 + rA;
        if (r >= NN) r = NN - 1;                  // clamp tail rows (stores masked below)
        ap[rf] = Ab + (size_t)r * 512 + kA;
    }
    const unsigned short* bp = Bp + (size_t)l * 8;

    short8 a0[4], b0[8], a1[4], b1[8];
    LOADA(a0, 0)
    LOADB(b0, 0)
    #pragma unroll 1
    for (int kc = 0; kc < 16; kc += 2) {
        LOADA(a1, kc + 1)
        MFMA_HALF(a0, b0, 0, 1)
        LOADB(b1, kc + 1)
        MFMA_HALF(a0, b0, 2, 3)
        if (kc + 2 < 16) LOADA(a0, kc + 2)
        MFMA_HALF(a1, b1, 0, 1)
        if (kc + 2 < 16) LOADB(b0, kc + 2)
        MFMA_HALF(a1, b1, 2, 3)
    }

    __syncthreads();   // Ab aliases out: all waves' A reads must finish before stores

    #pragma unroll
    for (int rf = 0; rf < 4; ++rf) {
        const int rb = row0 + rf * 16 + (l >> 4) * 4;
        #pragma unroll
        for (int c = 0; c < 4; ++c) {
            const int gg = w * 64 + c * 16 + (l & 15);
            const float bv0 = bias[gg], bv1 = bias[256 + gg];
            #pragma unroll
            for (int j = 0; j < 4; ++j) {
                int r = rb + j;
                if (r < NN) {
                    float c0 = acc[rf][c][j] + bv0;
                    float c1 = acc[rf][c + 4][j] + bv1;
                    float arma = 0.5f * (fmaxf(c0, 0.f) + fmaxf(c1, 0.f));
                    out[(size_t)r * FF + gg] = x[(size_t)r * FF + gg] + fmaxf(arma, 0.f);
                }
            }
        }
    }
}

extern "C" void kernel_launch(void* const* d_in, const int* in_sizes, int n_in,
                              void* d_out, int out_size, void* d_ws, size_t ws_size,
                              hipStream_t stream) {
    const float* x    = (const float*)d_in[0];
    const int*   ei   = (const int*)d_in[1];
    const float* wi   = (const float*)d_in[2];
    const float* wr   = (const float*)d_in[3];
    const float* bias = (const float*)d_in[4];
    float* out = (float*)d_out;

    // workspace (~2.6 MB)
    int*   deg     = (int*)d_ws;              // NN
    int*   off     = deg + NN;                // NN
    int*   cur     = off + NN;                // NN
    int*   csr_src = cur + NN;                // NE
    float* dinv    = (float*)(csr_src + NE);  // NN
    int*   bsum    = (int*)(dinv + NN);       // SCAN_B
    int*   boff    = bsum + SCAN_B;           // SCAN_B
    unsigned short* Bp = (unsigned short*)(boff + SCAN_B);   // 512*512 bf16 = 512 KB
    unsigned short* Ab = (unsigned short*)d_out;             // 50000 x 512 bf16 == d_out bytes

    hipMemsetAsync(deg, 0, NN * sizeof(int), stream);

    k_deg  <<<(NE + 255) / 256, 256, 0, stream>>>(ei, deg);
    k_scan1<<<SCAN_B, 256, 0, stream>>>(deg, bsum);
    k_scan2<<<1, 256, 0, stream>>>(bsum, boff);
    k_scan3<<<SCAN_B, 256, 0, stream>>>(deg, boff, off, cur, dinv);
    k_fill <<<(NE + 255) / 256, 256, 0, stream>>>(ei, cur, csr_src);
    k_bprep<<<128, 256, 0, stream>>>(wi, wr, Bp);
    k_agg  <<<(NN * 64 + 255) / 256, 256, 0, stream>>>(off, deg, csr_src, dinv, x, Ab);
    k_mm   <<<(NN + 63) / 64, 256, 0, stream>>>(Ab, Bp, x, bias, out);
}